// Round 4
// baseline (220.858 us; speedup 1.0000x reference)
//
#include <hip/hip_runtime.h>
#include <hip/hip_fp16.h>

#define NNODES 8192
#define NEDGES 262144
#define NNOUT 67108864L   // 8192*8192

typedef _Float16 half8 __attribute__((ext_vector_type(8)));
typedef _Float16 half4 __attribute__((ext_vector_type(4)));
typedef float float4v __attribute__((ext_vector_type(4)));

// ---------------- prep: transpose weights to [n][k] fp16 hi/lo, build bz, zero degrees ----------------
// W1th/W1tl [256][256]; Wzth/Wztl [64][256] (cols 0..31 = W2[:, :32], 32..63 = W3); bz[64]

__global__ __launch_bounds__(256) void prep_kernel(const float* __restrict__ W1, const float* __restrict__ W2,
                                                   const float* __restrict__ W3, const float* __restrict__ b2,
                                                   const float* __restrict__ b3, _Float16* __restrict__ W1th,
                                                   _Float16* __restrict__ W1tl, _Float16* __restrict__ Wzth,
                                                   _Float16* __restrict__ Wztl, float* __restrict__ bz,
                                                   int* __restrict__ degs) {
  int b = blockIdx.x, t = threadIdx.x;
  // W1 transpose: k=b, n=t
  float w = W1[b * 256 + t];
  _Float16 wh = (_Float16)w;
  W1th[t * 256 + b] = wh;
  W1tl[t * 256 + b] = (_Float16)(w - (float)wh);
  if (b >= 64 && b < 128) {
    int c = b - 64;
    float v = (c < 32) ? W2[t * 256 + c] : W3[t * 32 + (c - 32)];
    _Float16 vh = (_Float16)v;
    Wzth[c * 256 + t] = vh;
    Wztl[c * 256 + t] = (_Float16)(v - (float)vh);
  }
  if (b == 128 && t < 64) bz[t] = (t < 32) ? b2[t] : b3[t - 32];
  if (b >= 192) degs[(b - 192) * 256 + t] = 0;
}

__global__ __launch_bounds__(256) void deg_kernel(const int* __restrict__ src, const int* __restrict__ dst,
                                                  int* __restrict__ out_deg, int* __restrict__ in_deg) {
  int e = blockIdx.x * 256 + threadIdx.x;
  if (e < NEDGES) {
    atomicAdd(&out_deg[src[e]], 1);
    atomicAdd(&in_deg[dst[e]], 1);
  }
}

// single block: scan in_deg -> row_ptr/cursor, compute degree norms
__global__ __launch_bounds__(256) void scan_norm_kernel(const int* __restrict__ in_deg,
                                                        const int* __restrict__ out_deg,
                                                        int* __restrict__ row_ptr, int* __restrict__ cursor,
                                                        float* __restrict__ norm_src, float* __restrict__ norm_dst) {
  __shared__ int partial[256];
  int t = threadIdx.x;
  int base = t * 32;
  int local[32];
  int s = 0;
#pragma unroll
  for (int i = 0; i < 32; ++i) { local[i] = in_deg[base + i]; s += local[i]; }
  partial[t] = s;
  __syncthreads();
  for (int off = 1; off < 256; off <<= 1) {
    int v = (t >= off) ? partial[t - off] : 0;
    __syncthreads();
    partial[t] += v;
    __syncthreads();
  }
  int run = (t == 0) ? 0 : partial[t - 1];
  if (t == 0) row_ptr[0] = 0;
#pragma unroll
  for (int i = 0; i < 32; ++i) {
    int od = out_deg[base + i]; if (od < 1) od = 1;
    int id = local[i]; if (id < 1) id = 1;
    norm_src[base + i] = rsqrtf((float)od);
    norm_dst[base + i] = rsqrtf((float)id);
    cursor[base + i] = run;
    run += local[i];
    row_ptr[base + i + 1] = run;
  }
}

// scatter CSR + convert xs = (half)(features * norm_src[row]); 2048 blocks
__global__ __launch_bounds__(256) void scatter_convert(const int* __restrict__ src, const int* __restrict__ dst,
                                                       int* __restrict__ cursor, int* __restrict__ csr,
                                                       const float* __restrict__ x, const float* __restrict__ norm_src,
                                                       _Float16* __restrict__ xs) {
  int b = blockIdx.x, t = threadIdx.x;
  if (b < 1024) {
    int e = b * 256 + t;
    int d = dst[e];
    int pos = atomicAdd(&cursor[d], 1);
    csr[pos] = src[e];
  }
  int i = b * 256 + t;          // 524288 threads, 4 elems each
  int base = i * 4;
  float ns = norm_src[base >> 8];
  float4 v = *(const float4*)(x + base);
  half4 o = {(_Float16)(v.x * ns), (_Float16)(v.y * ns), (_Float16)(v.z * ns), (_Float16)(v.w * ns)};
  *(half4*)(xs + base) = o;
}

// ---------------- propagation: Q[v] = norm_dst[v] * sum xs[src]; output fp16 hi/lo ----------------
// 1 wave per node (64 lanes x half4 = 256 cols), 4 nodes per block

__global__ __launch_bounds__(256) void propagate_hl(const _Float16* __restrict__ xs, _Float16* __restrict__ Qh,
                                                    _Float16* __restrict__ Ql, const int* __restrict__ row_ptr,
                                                    const int* __restrict__ csr, const float* __restrict__ norm_dst) {
  int v = blockIdx.x * 4 + (threadIdx.x >> 6);
  int lane = threadIdx.x & 63;
  int beg = row_ptr[v], end = row_ptr[v + 1];
  float a0 = 0.f, a1 = 0.f, a2 = 0.f, a3 = 0.f;
  const _Float16* base = xs + 4 * lane;
  int e = beg;
  for (; e + 4 <= end; e += 4) {
    int s0 = csr[e], s1 = csr[e + 1], s2 = csr[e + 2], s3 = csr[e + 3];
    half4 v0 = *(const half4*)(base + (long)s0 * 256);
    half4 v1 = *(const half4*)(base + (long)s1 * 256);
    half4 v2 = *(const half4*)(base + (long)s2 * 256);
    half4 v3 = *(const half4*)(base + (long)s3 * 256);
    a0 += (float)v0.x + (float)v1.x + (float)v2.x + (float)v3.x;
    a1 += (float)v0.y + (float)v1.y + (float)v2.y + (float)v3.y;
    a2 += (float)v0.z + (float)v1.z + (float)v2.z + (float)v3.z;
    a3 += (float)v0.w + (float)v1.w + (float)v2.w + (float)v3.w;
  }
  for (; e < end; ++e) {
    half4 v0 = *(const half4*)(base + (long)csr[e] * 256);
    a0 += (float)v0.x; a1 += (float)v0.y; a2 += (float)v0.z; a3 += (float)v0.w;
  }
  float nd = norm_dst[v];
  a0 *= nd; a1 *= nd; a2 *= nd; a3 *= nd;
  _Float16 h0 = (_Float16)a0, h1 = (_Float16)a1, h2 = (_Float16)a2, h3 = (_Float16)a3;
  half4 qh = {h0, h1, h2, h3};
  half4 ql = {(_Float16)(a0 - (float)h0), (_Float16)(a1 - (float)h1),
              (_Float16)(a2 - (float)h2), (_Float16)(a3 - (float)h3)};
  *(half4*)(Qh + (long)v * 256 + 4 * lane) = qh;
  *(half4*)(Ql + (long)v * 256 + 4 * lane) = ql;
}

// ---------------- GEMM1 (MFMA): xs = (half)(relu(Q@W1 + b1) * norm_src) ----------------
// grid (128,2): 64 rows x 128 cols per block; wave = 16 rows x 128 cols

__global__ __launch_bounds__(256) void gemm1_mfma(const _Float16* __restrict__ Qh, const _Float16* __restrict__ Ql,
                                                  const _Float16* __restrict__ W1th, const _Float16* __restrict__ W1tl,
                                                  const float* __restrict__ b1, const float* __restrict__ norm_src,
                                                  _Float16* __restrict__ xs) {
  int tid = threadIdx.x;
  int wave = tid >> 6, lane = tid & 63;
  int l15 = lane & 15, lk = (lane >> 4) * 8;
  long rowBase = blockIdx.x * 64 + wave * 16;
  int colBase = blockIdx.y * 128;
  float4v acc[8] = {};
  for (int ks = 0; ks < 8; ++ks) {
    int k0 = ks * 32;
    half8 ah = *(const half8*)(Qh + (rowBase + l15) * 256 + k0 + lk);
    half8 al = *(const half8*)(Ql + (rowBase + l15) * 256 + k0 + lk);
#pragma unroll
    for (int ct = 0; ct < 8; ++ct) {
      long bo = (long)(colBase + ct * 16 + l15) * 256 + k0 + lk;
      half8 bh = *(const half8*)(W1th + bo);
      half8 bl = *(const half8*)(W1tl + bo);
      acc[ct] = __builtin_amdgcn_mfma_f32_16x16x32_f16(al, bh, acc[ct], 0, 0, 0);
      acc[ct] = __builtin_amdgcn_mfma_f32_16x16x32_f16(ah, bl, acc[ct], 0, 0, 0);
      acc[ct] = __builtin_amdgcn_mfma_f32_16x16x32_f16(ah, bh, acc[ct], 0, 0, 0);
    }
  }
  int crow = (lane >> 4) * 4;
#pragma unroll
  for (int ct = 0; ct < 8; ++ct) {
    int c = colBase + ct * 16 + l15;
    float bb = b1[c];
#pragma unroll
    for (int r = 0; r < 4; ++r) {
      long row = rowBase + crow + r;
      float v = fmaxf(acc[ct][r] + bb, 0.f) * norm_src[row];
      xs[row * 256 + c] = (_Float16)v;
    }
  }
}

// ---------------- GEMMZ (MFMA) + z combine + hi/lo split ----------------
// grid 128: 64 rows per block; wave = 16 rows x 64 cols (ct0,1 = mean, ct2,3 = log_std)

__global__ __launch_bounds__(256) void gemmz_mfma(const _Float16* __restrict__ Qh, const _Float16* __restrict__ Ql,
                                                  const _Float16* __restrict__ Wzth, const _Float16* __restrict__ Wztl,
                                                  const float* __restrict__ bz, const float* __restrict__ noise,
                                                  float* __restrict__ zout, _Float16* __restrict__ Zh,
                                                  _Float16* __restrict__ Zl) {
  int tid = threadIdx.x;
  int wave = tid >> 6, lane = tid & 63;
  int l15 = lane & 15, lk = (lane >> 4) * 8;
  long rowBase = blockIdx.x * 64 + wave * 16;
  float4v acc[4] = {};
  for (int ks = 0; ks < 8; ++ks) {
    int k0 = ks * 32;
    half8 ah = *(const half8*)(Qh + (rowBase + l15) * 256 + k0 + lk);
    half8 al = *(const half8*)(Ql + (rowBase + l15) * 256 + k0 + lk);
#pragma unroll
    for (int ct = 0; ct < 4; ++ct) {
      long bo = (long)(ct * 16 + l15) * 256 + k0 + lk;
      half8 bh = *(const half8*)(Wzth + bo);
      half8 bl = *(const half8*)(Wztl + bo);
      acc[ct] = __builtin_amdgcn_mfma_f32_16x16x32_f16(al, bh, acc[ct], 0, 0, 0);
      acc[ct] = __builtin_amdgcn_mfma_f32_16x16x32_f16(ah, bl, acc[ct], 0, 0, 0);
      acc[ct] = __builtin_amdgcn_mfma_f32_16x16x32_f16(ah, bh, acc[ct], 0, 0, 0);
    }
  }
  int crow = (lane >> 4) * 4;
  float bm0 = bz[l15], bm1 = bz[16 + l15], bs0 = bz[32 + l15], bs1 = bz[48 + l15];
#pragma unroll
  for (int r = 0; r < 4; ++r) {
    long row = rowBase + crow + r;
    float me0 = fmaxf(acc[0][r] + bm0, 0.f);
    float me1 = fmaxf(acc[1][r] + bm1, 0.f);
    float ls0 = fmaxf(acc[2][r] + bs0, 0.f);
    float ls1 = fmaxf(acc[3][r] + bs1, 0.f);
    float n0 = noise[row * 32 + l15];
    float n1 = noise[row * 32 + 16 + l15];
    float z0 = me0 + n0 * __expf(ls0);
    float z1 = me1 + n1 * __expf(ls1);
    zout[row * 32 + l15] = z0;
    zout[row * 32 + 16 + l15] = z1;
    _Float16 h0 = (_Float16)z0, h1 = (_Float16)z1;
    Zh[row * 32 + l15] = h0;
    Zl[row * 32 + l15] = (_Float16)(z0 - (float)h0);
    Zh[row * 32 + 16 + l15] = h1;
    Zl[row * 32 + 16 + l15] = (_Float16)(z1 - (float)h1);
  }
}

// ---------------- adj = sigmoid(Z @ Z^T) MFMA + seq_fts (merged) ----------------
// grid (68,64): x<64 -> adj 128x128 tile; x>=64 -> seq block (x-64)*64 + y

__global__ __launch_bounds__(256) void adj_seq(const _Float16* __restrict__ Zh, const _Float16* __restrict__ Zl,
                                               float* __restrict__ out, const float* __restrict__ F,
                                               const float* __restrict__ Wf, float* __restrict__ seq) {
  int tid = threadIdx.x;
  if (blockIdx.x >= 64) {
    int sb = (blockIdx.x - 64) * 64 + blockIdx.y;
    int t = sb * 256 + tid;
    int row = t >> 3;
    int cq = (t & 7) * 4;
    float a0 = 0.f, a1 = 0.f, a2 = 0.f, a3 = 0.f;
    const float* frow = F + row * 256;
    for (int k = 0; k < 256; k += 4) {
      float4 fv = *(const float4*)(frow + k);
      float4 w0 = *(const float4*)(Wf + k * 32 + cq);
      float4 w1 = *(const float4*)(Wf + (k + 1) * 32 + cq);
      float4 w2 = *(const float4*)(Wf + (k + 2) * 32 + cq);
      float4 w3 = *(const float4*)(Wf + (k + 3) * 32 + cq);
      a0 = fmaf(fv.x, w0.x, fmaf(fv.y, w1.x, fmaf(fv.z, w2.x, fmaf(fv.w, w3.x, a0))));
      a1 = fmaf(fv.x, w0.y, fmaf(fv.y, w1.y, fmaf(fv.z, w2.y, fmaf(fv.w, w3.y, a1))));
      a2 = fmaf(fv.x, w0.z, fmaf(fv.y, w1.z, fmaf(fv.z, w2.z, fmaf(fv.w, w3.z, a2))));
      a3 = fmaf(fv.x, w0.w, fmaf(fv.y, w1.w, fmaf(fv.z, w2.w, fmaf(fv.w, w3.w, a3))));
    }
    float4 o = {a0, a1, a2, a3};
    *(float4*)&seq[row * 32 + cq] = o;
    return;
  }
  int wave = tid >> 6;
  int lane = tid & 63;
  long rowBase = (long)blockIdx.y * 128 + wave * 32;
  long colBase = (long)blockIdx.x * 128;
  int l15 = lane & 15;
  int lk = (lane >> 4) * 8;
  half8 ah0 = *(const half8*)(Zh + (rowBase + l15) * 32 + lk);
  half8 al0 = *(const half8*)(Zl + (rowBase + l15) * 32 + lk);
  half8 ah1 = *(const half8*)(Zh + (rowBase + 16 + l15) * 32 + lk);
  half8 al1 = *(const half8*)(Zl + (rowBase + 16 + l15) * 32 + lk);
  int crow = (lane >> 4) * 4;
#pragma unroll
  for (int ct = 0; ct < 8; ++ct) {
    half8 bh = *(const half8*)(Zh + (colBase + ct * 16 + l15) * 32 + lk);
    half8 bl = *(const half8*)(Zl + (colBase + ct * 16 + l15) * 32 + lk);
    float4v acc0 = {}, acc1 = {};
    acc0 = __builtin_amdgcn_mfma_f32_16x16x32_f16(al0, bh, acc0, 0, 0, 0);
    acc0 = __builtin_amdgcn_mfma_f32_16x16x32_f16(ah0, bl, acc0, 0, 0, 0);
    acc0 = __builtin_amdgcn_mfma_f32_16x16x32_f16(ah0, bh, acc0, 0, 0, 0);
    acc1 = __builtin_amdgcn_mfma_f32_16x16x32_f16(al1, bh, acc1, 0, 0, 0);
    acc1 = __builtin_amdgcn_mfma_f32_16x16x32_f16(ah1, bl, acc1, 0, 0, 0);
    acc1 = __builtin_amdgcn_mfma_f32_16x16x32_f16(ah1, bh, acc1, 0, 0, 0);
    long c = colBase + ct * 16 + l15;
#pragma unroll
    for (int r = 0; r < 4; ++r) {
      float s0 = __builtin_amdgcn_rcpf(1.f + __expf(-acc0[r]));
      float s1 = __builtin_amdgcn_rcpf(1.f + __expf(-acc1[r]));
      __builtin_nontemporal_store(s0, &out[(rowBase + crow + r) * 8192 + c]);
      __builtin_nontemporal_store(s1, &out[(rowBase + 16 + crow + r) * 8192 + c]);
    }
  }
}

// ---------------- launcher ----------------

extern "C" void kernel_launch(void* const* d_in, const int* in_sizes, int n_in,
                              void* d_out, int out_size, void* d_ws, size_t ws_size,
                              hipStream_t stream) {
  const float* features = (const float*)d_in[0];
  const float* noise    = (const float*)d_in[1];
  const int*   src      = (const int*)d_in[2];
  const int*   dst      = (const int*)d_in[3];
  const float* W1       = (const float*)d_in[4];
  const float* b1       = (const float*)d_in[5];
  const float* W2       = (const float*)d_in[6];
  const float* b2       = (const float*)d_in[7];
  const float* W3       = (const float*)d_in[8];
  const float* b3       = (const float*)d_in[9];
  const float* fcw      = (const float*)d_in[10];

  float* out = (float*)d_out;

  // ws layout (4B units): same footprint as round 2 (~2.3 MB)
  int* ws_i    = (int*)d_ws;
  int* out_deg = ws_i;                 // 8192
  int* in_deg  = ws_i + 8192;          // 8192
  int* row_ptr = ws_i + 16384;         // 8193
  int* cursor  = ws_i + 24832;         // 8192
  int* csr     = ws_i + 33024;         // 262144
  float* norm_src = (float*)(ws_i + 295168);  // 8192
  float* norm_dst = (float*)(ws_i + 303360);  // 8192
  _Float16* Zh = (_Float16*)(ws_i + 311552);  // 262144 halves
  _Float16* Zl = (_Float16*)(ws_i + 442624);  // 262144 halves

  // big intermediates live in the adj region of d_out (all dead before adj_seq runs)
  float* adj      = out;
  float* zbuf     = out + NNOUT;              // final output z [8192*32]
  float* seq      = out + NNOUT + 262144;     // final output seq_fts [8192*32]
  _Float16* xs    = (_Float16*)out;                   // [8192][256] fp16 (1M floats)
  _Float16* Qh    = (_Float16*)(out + 1048576);       // [8192][256] fp16 hi
  _Float16* Ql    = (_Float16*)(out + 2097152);       // [8192][256] fp16 lo
  _Float16* W1th  = (_Float16*)(out + 3145728);       // [256][256]
  _Float16* W1tl  = (_Float16*)(out + 3178496);
  _Float16* Wzth  = (_Float16*)(out + 3211264);       // [64][256]
  _Float16* Wztl  = (_Float16*)(out + 3219456);
  float*    bz    = out + 3227648;                    // [64]

  prep_kernel<<<256, 256, 0, stream>>>(W1, W2, W3, b2, b3, W1th, W1tl, Wzth, Wztl, bz, out_deg);
  deg_kernel<<<NEDGES / 256, 256, 0, stream>>>(src, dst, out_deg, in_deg);
  scan_norm_kernel<<<1, 256, 0, stream>>>(in_deg, out_deg, row_ptr, cursor, norm_src, norm_dst);
  scatter_convert<<<2048, 256, 0, stream>>>(src, dst, cursor, csr, features, norm_src, xs);

  propagate_hl<<<2048, 256, 0, stream>>>(xs, Qh, Ql, row_ptr, csr, norm_dst);
  gemm1_mfma<<<dim3(128, 2), 256, 0, stream>>>(Qh, Ql, W1th, W1tl, b1, norm_src, xs);

  propagate_hl<<<2048, 256, 0, stream>>>(xs, Qh, Ql, row_ptr, csr, norm_dst);
  gemmz_mfma<<<128, 256, 0, stream>>>(Qh, Ql, Wzth, Wztl, bz, noise, zbuf, Zh, Zl);

  adj_seq<<<dim3(68, 64), 256, 0, stream>>>(Zh, Zl, adj, features, fcw, seq);
}

// Round 5
// 206.690 us; speedup vs baseline: 1.0685x; 1.0685x over previous
//
#include <hip/hip_runtime.h>
#include <hip/hip_fp16.h>

#define NNODES 8192
#define NEDGES 262144
#define NNOUT 67108864L   // 8192*8192

typedef _Float16 half8 __attribute__((ext_vector_type(8)));
typedef _Float16 half4 __attribute__((ext_vector_type(4)));
typedef float float4v __attribute__((ext_vector_type(4)));

// ---------------- prep: transpose weights to [n][k] fp16 hi/lo, build bz, zero degrees ----------------

__global__ __launch_bounds__(256) void prep_kernel(const float* __restrict__ W1, const float* __restrict__ W2,
                                                   const float* __restrict__ W3, const float* __restrict__ b2,
                                                   const float* __restrict__ b3, _Float16* __restrict__ W1th,
                                                   _Float16* __restrict__ W1tl, _Float16* __restrict__ Wzth,
                                                   _Float16* __restrict__ Wztl, float* __restrict__ bz,
                                                   int* __restrict__ degs) {
  int b = blockIdx.x, t = threadIdx.x;
  float w = W1[b * 256 + t];
  _Float16 wh = (_Float16)w;
  W1th[t * 256 + b] = wh;
  W1tl[t * 256 + b] = (_Float16)(w - (float)wh);
  if (b >= 64 && b < 128) {
    int c = b - 64;
    float v = (c < 32) ? W2[t * 256 + c] : W3[t * 32 + (c - 32)];
    _Float16 vh = (_Float16)v;
    Wzth[c * 256 + t] = vh;
    Wztl[c * 256 + t] = (_Float16)(v - (float)vh);
  }
  if (b == 128 && t < 64) bz[t] = (t < 32) ? b2[t] : b3[t - 32];
  if (b >= 192) degs[(b - 192) * 256 + t] = 0;
}

__global__ __launch_bounds__(256) void deg_kernel(const int* __restrict__ src, const int* __restrict__ dst,
                                                  int* __restrict__ out_deg, int* __restrict__ in_deg) {
  int e = blockIdx.x * 256 + threadIdx.x;
  if (e < NEDGES) {
    atomicAdd(&out_deg[src[e]], 1);
    atomicAdd(&in_deg[dst[e]], 1);
  }
}

// single block: scan in_deg -> row_ptr/cursor, compute degree norms
__global__ __launch_bounds__(256) void scan_norm_kernel(const int* __restrict__ in_deg,
                                                        const int* __restrict__ out_deg,
                                                        int* __restrict__ row_ptr, int* __restrict__ cursor,
                                                        float* __restrict__ norm_src, float* __restrict__ norm_dst) {
  __shared__ int partial[256];
  int t = threadIdx.x;
  int base = t * 32;
  int local[32];
  int s = 0;
#pragma unroll
  for (int i = 0; i < 32; ++i) { local[i] = in_deg[base + i]; s += local[i]; }
  partial[t] = s;
  __syncthreads();
  for (int off = 1; off < 256; off <<= 1) {
    int v = (t >= off) ? partial[t - off] : 0;
    __syncthreads();
    partial[t] += v;
    __syncthreads();
  }
  int run = (t == 0) ? 0 : partial[t - 1];
  if (t == 0) row_ptr[0] = 0;
#pragma unroll
  for (int i = 0; i < 32; ++i) {
    int od = out_deg[base + i]; if (od < 1) od = 1;
    int id = local[i]; if (id < 1) id = 1;
    norm_src[base + i] = rsqrtf((float)od);
    norm_dst[base + i] = rsqrtf((float)id);
    cursor[base + i] = run;
    run += local[i];
    row_ptr[base + i + 1] = run;
  }
}

// scatter CSR + convert xs = (half)(features * norm_src[row]) + seq_fts (independent blocks)
__global__ __launch_bounds__(256) void scatter_convert_seq(const int* __restrict__ src, const int* __restrict__ dst,
                                                           int* __restrict__ cursor, int* __restrict__ csr,
                                                           const float* __restrict__ x,
                                                           const float* __restrict__ norm_src,
                                                           _Float16* __restrict__ xs, const float* __restrict__ Wf,
                                                           float* __restrict__ seq) {
  int b = blockIdx.x, t = threadIdx.x;
  if (b >= 2048) {
    // seq_fts = features @ fc_w : blocks 2048..2303, 65536 threads, row each 8 threads
    int tt = (b - 2048) * 256 + t;
    int row = tt >> 3;
    int cq = (tt & 7) * 4;
    float a0 = 0.f, a1 = 0.f, a2 = 0.f, a3 = 0.f;
    const float* frow = x + row * 256;
    for (int k = 0; k < 256; k += 4) {
      float4 fv = *(const float4*)(frow + k);
      float4 w0 = *(const float4*)(Wf + k * 32 + cq);
      float4 w1 = *(const float4*)(Wf + (k + 1) * 32 + cq);
      float4 w2 = *(const float4*)(Wf + (k + 2) * 32 + cq);
      float4 w3 = *(const float4*)(Wf + (k + 3) * 32 + cq);
      a0 = fmaf(fv.x, w0.x, fmaf(fv.y, w1.x, fmaf(fv.z, w2.x, fmaf(fv.w, w3.x, a0))));
      a1 = fmaf(fv.x, w0.y, fmaf(fv.y, w1.y, fmaf(fv.z, w2.y, fmaf(fv.w, w3.y, a1))));
      a2 = fmaf(fv.x, w0.z, fmaf(fv.y, w1.z, fmaf(fv.z, w2.z, fmaf(fv.w, w3.z, a2))));
      a3 = fmaf(fv.x, w0.w, fmaf(fv.y, w1.w, fmaf(fv.z, w2.w, fmaf(fv.w, w3.w, a3))));
    }
    float4 o = {a0, a1, a2, a3};
    *(float4*)&seq[row * 32 + cq] = o;
    return;
  }
  if (b < 1024) {
    int e = b * 256 + t;
    int d = dst[e];
    int pos = atomicAdd(&cursor[d], 1);
    csr[pos] = src[e];
  }
  int i = b * 256 + t;          // 524288 threads, 4 elems each
  int base = i * 4;
  float ns = norm_src[base >> 8];
  float4 v = *(const float4*)(x + base);
  half4 o = {(_Float16)(v.x * ns), (_Float16)(v.y * ns), (_Float16)(v.z * ns), (_Float16)(v.w * ns)};
  *(half4*)(xs + base) = o;
}

// ---------------- propagation: Q[v] = norm_dst[v] * sum xs[src]; output fp16 hi/lo ----------------

__global__ __launch_bounds__(256) void propagate_hl(const _Float16* __restrict__ xs, _Float16* __restrict__ Qh,
                                                    _Float16* __restrict__ Ql, const int* __restrict__ row_ptr,
                                                    const int* __restrict__ csr, const float* __restrict__ norm_dst) {
  int v = blockIdx.x * 4 + (threadIdx.x >> 6);
  int lane = threadIdx.x & 63;
  int beg = row_ptr[v], end = row_ptr[v + 1];
  float a0 = 0.f, a1 = 0.f, a2 = 0.f, a3 = 0.f;
  const _Float16* base = xs + 4 * lane;
  int e = beg;
  for (; e + 4 <= end; e += 4) {
    int s0 = csr[e], s1 = csr[e + 1], s2 = csr[e + 2], s3 = csr[e + 3];
    half4 v0 = *(const half4*)(base + (long)s0 * 256);
    half4 v1 = *(const half4*)(base + (long)s1 * 256);
    half4 v2 = *(const half4*)(base + (long)s2 * 256);
    half4 v3 = *(const half4*)(base + (long)s3 * 256);
    a0 += (float)v0.x + (float)v1.x + (float)v2.x + (float)v3.x;
    a1 += (float)v0.y + (float)v1.y + (float)v2.y + (float)v3.y;
    a2 += (float)v0.z + (float)v1.z + (float)v2.z + (float)v3.z;
    a3 += (float)v0.w + (float)v1.w + (float)v2.w + (float)v3.w;
  }
  for (; e < end; ++e) {
    half4 v0 = *(const half4*)(base + (long)csr[e] * 256);
    a0 += (float)v0.x; a1 += (float)v0.y; a2 += (float)v0.z; a3 += (float)v0.w;
  }
  float nd = norm_dst[v];
  a0 *= nd; a1 *= nd; a2 *= nd; a3 *= nd;
  _Float16 h0 = (_Float16)a0, h1 = (_Float16)a1, h2 = (_Float16)a2, h3 = (_Float16)a3;
  half4 qh = {h0, h1, h2, h3};
  half4 ql = {(_Float16)(a0 - (float)h0), (_Float16)(a1 - (float)h1),
              (_Float16)(a2 - (float)h2), (_Float16)(a3 - (float)h3)};
  *(half4*)(Qh + (long)v * 256 + 4 * lane) = qh;
  *(half4*)(Ql + (long)v * 256 + 4 * lane) = ql;
}

// ---------------- GEMM1 (MFMA): xs = (half)(relu(Q@W1 + b1) * norm_src) ----------------

__global__ __launch_bounds__(256) void gemm1_mfma(const _Float16* __restrict__ Qh, const _Float16* __restrict__ Ql,
                                                  const _Float16* __restrict__ W1th, const _Float16* __restrict__ W1tl,
                                                  const float* __restrict__ b1, const float* __restrict__ norm_src,
                                                  _Float16* __restrict__ xs) {
  int tid = threadIdx.x;
  int wave = tid >> 6, lane = tid & 63;
  int l15 = lane & 15, lk = (lane >> 4) * 8;
  long rowBase = blockIdx.x * 64 + wave * 16;
  int colBase = blockIdx.y * 128;
  float4v acc[8] = {};
  for (int ks = 0; ks < 8; ++ks) {
    int k0 = ks * 32;
    half8 ah = *(const half8*)(Qh + (rowBase + l15) * 256 + k0 + lk);
    half8 al = *(const half8*)(Ql + (rowBase + l15) * 256 + k0 + lk);
#pragma unroll
    for (int ct = 0; ct < 8; ++ct) {
      long bo = (long)(colBase + ct * 16 + l15) * 256 + k0 + lk;
      half8 bh = *(const half8*)(W1th + bo);
      half8 bl = *(const half8*)(W1tl + bo);
      acc[ct] = __builtin_amdgcn_mfma_f32_16x16x32_f16(al, bh, acc[ct], 0, 0, 0);
      acc[ct] = __builtin_amdgcn_mfma_f32_16x16x32_f16(ah, bl, acc[ct], 0, 0, 0);
      acc[ct] = __builtin_amdgcn_mfma_f32_16x16x32_f16(ah, bh, acc[ct], 0, 0, 0);
    }
  }
  int crow = (lane >> 4) * 4;
#pragma unroll
  for (int ct = 0; ct < 8; ++ct) {
    int c = colBase + ct * 16 + l15;
    float bb = b1[c];
#pragma unroll
    for (int r = 0; r < 4; ++r) {
      long row = rowBase + crow + r;
      float v = fmaxf(acc[ct][r] + bb, 0.f) * norm_src[row];
      xs[row * 256 + c] = (_Float16)v;
    }
  }
}

// ---------------- GEMMZ (MFMA) + z combine + hi/lo split ----------------

__global__ __launch_bounds__(256) void gemmz_mfma(const _Float16* __restrict__ Qh, const _Float16* __restrict__ Ql,
                                                  const _Float16* __restrict__ Wzth, const _Float16* __restrict__ Wztl,
                                                  const float* __restrict__ bz, const float* __restrict__ noise,
                                                  float* __restrict__ zout, _Float16* __restrict__ Zh,
                                                  _Float16* __restrict__ Zl) {
  int tid = threadIdx.x;
  int wave = tid >> 6, lane = tid & 63;
  int l15 = lane & 15, lk = (lane >> 4) * 8;
  long rowBase = blockIdx.x * 64 + wave * 16;
  float4v acc[4] = {};
  for (int ks = 0; ks < 8; ++ks) {
    int k0 = ks * 32;
    half8 ah = *(const half8*)(Qh + (rowBase + l15) * 256 + k0 + lk);
    half8 al = *(const half8*)(Ql + (rowBase + l15) * 256 + k0 + lk);
#pragma unroll
    for (int ct = 0; ct < 4; ++ct) {
      long bo = (long)(ct * 16 + l15) * 256 + k0 + lk;
      half8 bh = *(const half8*)(Wzth + bo);
      half8 bl = *(const half8*)(Wztl + bo);
      acc[ct] = __builtin_amdgcn_mfma_f32_16x16x32_f16(al, bh, acc[ct], 0, 0, 0);
      acc[ct] = __builtin_amdgcn_mfma_f32_16x16x32_f16(ah, bl, acc[ct], 0, 0, 0);
      acc[ct] = __builtin_amdgcn_mfma_f32_16x16x32_f16(ah, bh, acc[ct], 0, 0, 0);
    }
  }
  int crow = (lane >> 4) * 4;
  float bm0 = bz[l15], bm1 = bz[16 + l15], bs0 = bz[32 + l15], bs1 = bz[48 + l15];
#pragma unroll
  for (int r = 0; r < 4; ++r) {
    long row = rowBase + crow + r;
    float me0 = fmaxf(acc[0][r] + bm0, 0.f);
    float me1 = fmaxf(acc[1][r] + bm1, 0.f);
    float ls0 = fmaxf(acc[2][r] + bs0, 0.f);
    float ls1 = fmaxf(acc[3][r] + bs1, 0.f);
    float n0 = noise[row * 32 + l15];
    float n1 = noise[row * 32 + 16 + l15];
    float z0 = me0 + n0 * __expf(ls0);
    float z1 = me1 + n1 * __expf(ls1);
    zout[row * 32 + l15] = z0;
    zout[row * 32 + 16 + l15] = z1;
    _Float16 h0 = (_Float16)z0, h1 = (_Float16)z1;
    Zh[row * 32 + l15] = h0;
    Zl[row * 32 + l15] = (_Float16)(z0 - (float)h0);
    Zh[row * 32 + 16 + l15] = h1;
    Zl[row * 32 + 16 + l15] = (_Float16)(z1 - (float)h1);
  }
}

// ---------------- adj = sigmoid(Z @ Z^T) MFMA, LDS-transposed coalesced stores ----------------
// grid (64,64), 4 waves/block; wave owns 32 rows x 128 cols; epilogue via
// wave-private LDS slab [32][68] in two 64-col halves -> float4 coalesced stores.

__global__ __launch_bounds__(256) void adj_mfma(const _Float16* __restrict__ Zh, const _Float16* __restrict__ Zl,
                                                float* __restrict__ out) {
  __shared__ __align__(16) float lds[4][32][68];
  int tid = threadIdx.x;
  int wave = tid >> 6;
  int lane = tid & 63;
  long rowBase = (long)blockIdx.y * 128 + wave * 32;
  long colBase = (long)blockIdx.x * 128;
  int l15 = lane & 15;
  int lk = (lane >> 4) * 8;
  half8 ah0 = *(const half8*)(Zh + (rowBase + l15) * 32 + lk);
  half8 al0 = *(const half8*)(Zl + (rowBase + l15) * 32 + lk);
  half8 ah1 = *(const half8*)(Zh + (rowBase + 16 + l15) * 32 + lk);
  half8 al1 = *(const half8*)(Zl + (rowBase + 16 + l15) * 32 + lk);
  int crow = (lane >> 4) * 4;
  float* slab = &lds[wave][0][0];
#pragma unroll
  for (int h = 0; h < 2; ++h) {
#pragma unroll
    for (int ct = 0; ct < 4; ++ct) {
      int cg = h * 4 + ct;
      half8 bh = *(const half8*)(Zh + (colBase + cg * 16 + l15) * 32 + lk);
      half8 bl = *(const half8*)(Zl + (colBase + cg * 16 + l15) * 32 + lk);
      float4v acc0 = {}, acc1 = {};
      acc0 = __builtin_amdgcn_mfma_f32_16x16x32_f16(al0, bh, acc0, 0, 0, 0);
      acc0 = __builtin_amdgcn_mfma_f32_16x16x32_f16(ah0, bl, acc0, 0, 0, 0);
      acc0 = __builtin_amdgcn_mfma_f32_16x16x32_f16(ah0, bh, acc0, 0, 0, 0);
      acc1 = __builtin_amdgcn_mfma_f32_16x16x32_f16(al1, bh, acc1, 0, 0, 0);
      acc1 = __builtin_amdgcn_mfma_f32_16x16x32_f16(ah1, bl, acc1, 0, 0, 0);
      acc1 = __builtin_amdgcn_mfma_f32_16x16x32_f16(ah1, bh, acc1, 0, 0, 0);
#pragma unroll
      for (int r = 0; r < 4; ++r) {
        slab[(crow + r) * 68 + ct * 16 + l15] = __builtin_amdgcn_rcpf(1.f + __expf(-acc0[r]));
        slab[(16 + crow + r) * 68 + ct * 16 + l15] = __builtin_amdgcn_rcpf(1.f + __expf(-acc1[r]));
      }
    }
    __syncthreads();
#pragma unroll
    for (int i = 0; i < 8; ++i) {
      int rr = 4 * i + (lane >> 4);
      float4 v = *(const float4*)&slab[rr * 68 + 4 * l15];
      *(float4*)&out[(rowBase + rr) * 8192 + colBase + h * 64 + 4 * l15] = v;
    }
    __syncthreads();
  }
}

// ---------------- launcher ----------------

extern "C" void kernel_launch(void* const* d_in, const int* in_sizes, int n_in,
                              void* d_out, int out_size, void* d_ws, size_t ws_size,
                              hipStream_t stream) {
  const float* features = (const float*)d_in[0];
  const float* noise    = (const float*)d_in[1];
  const int*   src      = (const int*)d_in[2];
  const int*   dst      = (const int*)d_in[3];
  const float* W1       = (const float*)d_in[4];
  const float* b1       = (const float*)d_in[5];
  const float* W2       = (const float*)d_in[6];
  const float* b2       = (const float*)d_in[7];
  const float* W3       = (const float*)d_in[8];
  const float* b3       = (const float*)d_in[9];
  const float* fcw      = (const float*)d_in[10];

  float* out = (float*)d_out;

  // ws layout (4B units): ~2.3 MB
  int* ws_i    = (int*)d_ws;
  int* out_deg = ws_i;                 // 8192
  int* in_deg  = ws_i + 8192;          // 8192
  int* row_ptr = ws_i + 16384;         // 8193
  int* cursor  = ws_i + 24832;         // 8192
  int* csr     = ws_i + 33024;         // 262144
  float* norm_src = (float*)(ws_i + 295168);  // 8192
  float* norm_dst = (float*)(ws_i + 303360);  // 8192
  _Float16* Zh = (_Float16*)(ws_i + 311552);  // 262144 halves
  _Float16* Zl = (_Float16*)(ws_i + 442624);  // 262144 halves

  // big intermediates live in the adj region of d_out (all dead before adj_mfma runs)
  float* adj      = out;
  float* zbuf     = out + NNOUT;              // final output z [8192*32]
  float* seq      = out + NNOUT + 262144;     // final output seq_fts [8192*32]
  _Float16* xs    = (_Float16*)out;                   // [8192][256] fp16
  _Float16* Qh    = (_Float16*)(out + 1048576);       // [8192][256] fp16 hi
  _Float16* Ql    = (_Float16*)(out + 2097152);       // [8192][256] fp16 lo
  _Float16* W1th  = (_Float16*)(out + 3145728);       // [256][256]
  _Float16* W1tl  = (_Float16*)(out + 3178496);
  _Float16* Wzth  = (_Float16*)(out + 3211264);       // [64][256]
  _Float16* Wztl  = (_Float16*)(out + 3219456);
  float*    bz    = out + 3227648;                    // [64]

  prep_kernel<<<256, 256, 0, stream>>>(W1, W2, W3, b2, b3, W1th, W1tl, Wzth, Wztl, bz, out_deg);
  deg_kernel<<<NEDGES / 256, 256, 0, stream>>>(src, dst, out_deg, in_deg);
  scan_norm_kernel<<<1, 256, 0, stream>>>(in_deg, out_deg, row_ptr, cursor, norm_src, norm_dst);
  scatter_convert_seq<<<2304, 256, 0, stream>>>(src, dst, cursor, csr, features, norm_src, xs, fcw, seq);

  propagate_hl<<<2048, 256, 0, stream>>>(xs, Qh, Ql, row_ptr, csr, norm_dst);
  gemm1_mfma<<<dim3(128, 2), 256, 0, stream>>>(Qh, Ql, W1th, W1tl, b1, norm_src, xs);

  propagate_hl<<<2048, 256, 0, stream>>>(xs, Qh, Ql, row_ptr, csr, norm_dst);
  gemmz_mfma<<<128, 256, 0, stream>>>(Qh, Ql, Wzth, Wztl, bz, noise, zbuf, Zh, Zl);

  adj_mfma<<<dim3(64, 64), 256, 0, stream>>>(Zh, Zl, adj);
}